// Round 6
// baseline (176.801 us; speedup 1.0000x reference)
//
#include <hip/hip_runtime.h>
#include <cstddef>

typedef short short8 __attribute__((ext_vector_type(8)));
typedef unsigned short ushort8 __attribute__((ext_vector_type(8)));
typedef float f32x4 __attribute__((ext_vector_type(4)));

#define AS1(p) ((const __attribute__((address_space(1))) void*)(p))
#define AS3(p) ((__attribute__((address_space(3))) void*)(p))

__device__ __forceinline__ unsigned short f2bf(float f) {
  unsigned int u = __builtin_bit_cast(unsigned int, f);
  u += 0x7FFFu + ((u >> 16) & 1u);   // round-to-nearest-even
  return (unsigned short)(u >> 16);
}

__device__ __forceinline__ void gload_lds16(const void* g, void* l) {
  __builtin_amdgcn_global_load_lds(AS1(g), AS3(l), 16, 0, 0);
}

// ---------------------------------------------------------------------------
// fp32 -> bf16 elementwise convert
// ---------------------------------------------------------------------------
__global__ void cvt_f32_bf16(const float* __restrict__ in,
                             unsigned short* __restrict__ out, int n4) {
  int i = blockIdx.x * blockDim.x + threadIdx.x;
  if (i >= n4) return;
  float4 v = *reinterpret_cast<const float4*>(in + (size_t)i * 4);
  ushort4 o;
  o.x = f2bf(v.x); o.y = f2bf(v.y); o.z = f2bf(v.z); o.w = f2bf(v.w);
  *reinterpret_cast<ushort4*>(out + (size_t)i * 4) = o;
}

// ---------------------------------------------------------------------------
// fp32 [Kd][Nd] -> bf16 [Nd][Kd] tiled transpose+convert, block (32,8)
// ---------------------------------------------------------------------------
__global__ void transpose_cvt(const float* __restrict__ in,
                              unsigned short* __restrict__ out,
                              int Kd, int Nd) {
  __shared__ float tile[32][33];
  const int n0 = blockIdx.x * 32;
  const int k0 = blockIdx.y * 32;
  const int tx = threadIdx.x;
  const int ty = threadIdx.y;
#pragma unroll
  for (int i = 0; i < 4; ++i)
    tile[ty + i * 8][tx] = in[(size_t)(k0 + ty + i * 8) * Nd + n0 + tx];
  __syncthreads();
#pragma unroll
  for (int i = 0; i < 4; ++i)
    out[(size_t)(n0 + ty + i * 8) * Kd + k0 + tx] = f2bf(tile[tx][ty + i * 8]);
}

// ---------------------------------------------------------------------------
// GEMM: C[M][N] = A[M][K] * B'[N][K] (+bias or +C_old, optional relu+bf16 out)
// BM=128 x BN tile (BN=128 or 64), BK=64, 4 waves (2x2), 16x16x32 MFMA.
// ROUND-2 VERIFIED STRUCTURE (absmax 0.0156, 0 bank conflicts), with the
// round-6 occupancy lever: __launch_bounds__(256,4) -> 4-5 blocks/CU
// resident (m97 ran at ~3 blocks/CU; m114 cross-block implicit overlap is
// the stall-filler; m132 shows occupancy loss = -40%).
// LDS involution a^=((a>>7)&7)<<4 on pre-swizzled stage source + ds_read
// (both sides, rule #21). 1-D grid + bijective XCD-chunked swizzle.
// ---------------------------------------------------------------------------
template <int A_F32, int BN, int RELU_BF16_OUT>
__global__ __launch_bounds__(256, 4)
void gemm_bf16(const void* __restrict__ Ap, int lda,
               const unsigned short* __restrict__ B, int ldb,
               const float* __restrict__ bias,
               void* __restrict__ C, int ldc,
               int K, int beta, int nbx) {
  constexpr int BUNITS = BN / 32;          // 4-KB stage passes for B (4 or 2)
  constexpr int NB     = BN / 32;          // B frags per wave (4 or 2)
  __shared__ char lds[16384 + BN * 128];
  char* const As = lds;
  char* const Bs = lds + 16384;

  const int tid  = threadIdx.x;
  const int lane = tid & 63;
  const int w    = tid >> 6;
  const int wm   = w >> 1;
  const int wn   = w & 1;

  // bijective XCD-chunked swizzle (grid % 8 == 0 for all our launches)
  const int cpx     = gridDim.x >> 3;
  const int logical = (blockIdx.x & 7) * cpx + (blockIdx.x >> 3);
  const int m0 = (logical / nbx) * 128;
  const int n0 = (logical % nbx) * BN;

  f32x4 acc[4][NB];
#pragma unroll
  for (int i = 0; i < 4; ++i)
#pragma unroll
    for (int j = 0; j < NB; ++j)
      acc[i][j] = (f32x4){0.f, 0.f, 0.f, 0.f};

  // gload_lds staging map: linear LDS dest, pre-swizzled global source.
  int srow[4], scol[4], sbase[4];
#pragma unroll
  for (int j = 0; j < 4; ++j) {
    const int stored  = (j * 256 + tid) * 16;
    const int natural = stored ^ (((stored >> 7) & 7) << 4);
    srow[j]  = natural >> 7;          // logical tile row
    scol[j]  = (natural & 127) >> 1;  // logical k element (multiple of 8)
    sbase[j] = (j * 256 + (tid & 192)) * 16;  // wave-uniform LDS base
  }

  // A_F32 reg-staging map (fallback path): 4 groups of 8 f32 -> 8 bf16.
  size_t agofs[4];
  int ast[4];
  if (A_F32) {
#pragma unroll
    for (int p = 0; p < 4; ++p) {
      const int idx = p * 256 + tid;
      const int r   = idx >> 3;
      const int kbe = (idx & 7) * 8;
      agofs[p] = (size_t)(m0 + r) * lda + kbe;
      const int nat = r * 128 + kbe * 2;
      ast[p] = nat ^ (((nat >> 7) & 7) << 4);
    }
  }

  const int nsteps = K >> 6;
  for (int ks = 0; ks < nsteps; ++ks) {
    const int k0 = ks << 6;
    if (A_F32) {
      const float* Af = (const float*)Ap;
#pragma unroll
      for (int p = 0; p < 4; ++p) {
        const float* s = Af + agofs[p] + k0;
        float4 x0 = *reinterpret_cast<const float4*>(s);
        float4 x1 = *reinterpret_cast<const float4*>(s + 4);
        ushort8 v;
        v[0] = f2bf(x0.x); v[1] = f2bf(x0.y); v[2] = f2bf(x0.z); v[3] = f2bf(x0.w);
        v[4] = f2bf(x1.x); v[5] = f2bf(x1.y); v[6] = f2bf(x1.z); v[7] = f2bf(x1.w);
        *reinterpret_cast<ushort8*>(As + ast[p]) = v;
      }
    } else {
      const unsigned short* Ab = (const unsigned short*)Ap;
#pragma unroll
      for (int j = 0; j < 4; ++j)
        gload_lds16(Ab + (size_t)(m0 + srow[j]) * lda + (k0 + scol[j]),
                    As + sbase[j]);
    }
#pragma unroll
    for (int j = 0; j < BUNITS; ++j)
      gload_lds16(B + (size_t)(n0 + srow[j]) * ldb + (k0 + scol[j]),
                  Bs + sbase[j]);
    __syncthreads();   // drains vmcnt (gload_lds) + lgkmcnt (ds_write)

#pragma unroll
    for (int kk = 0; kk < 2; ++kk) {
      const int kb = kk * 64 + (lane >> 4) * 16;   // byte offset in row
      short8 af[4], bfv[NB];
#pragma unroll
      for (int mi = 0; mi < 4; ++mi) {
        int nat = (wm * 64 + mi * 16 + (lane & 15)) * 128 + kb;
        int st  = nat ^ (((nat >> 7) & 7) << 4);
        af[mi] = *reinterpret_cast<const short8*>(As + st);
      }
#pragma unroll
      for (int ni = 0; ni < NB; ++ni) {
        int nat = (wn * (BN / 2) + ni * 16 + (lane & 15)) * 128 + kb;
        int st  = nat ^ (((nat >> 7) & 7) << 4);
        bfv[ni] = *reinterpret_cast<const short8*>(Bs + st);
      }
#pragma unroll
      for (int mi = 0; mi < 4; ++mi)
#pragma unroll
        for (int ni = 0; ni < NB; ++ni)
          acc[mi][ni] = __builtin_amdgcn_mfma_f32_16x16x32_bf16(
              af[mi], bfv[ni], acc[mi][ni], 0, 0, 0);
    }
    __syncthreads();   // all reads done before next stage overwrites
  }

  // Epilogue: D row = (lane>>4)*4 + reg, col = lane&15 (m89-verified)
  const int row0 = m0 + wm * 64 + (lane >> 4) * 4;
  const int col0 = n0 + wn * (BN / 2) + (lane & 15);
#pragma unroll
  for (int ni = 0; ni < NB; ++ni) {
    const int c = col0 + ni * 16;
    const float bv = beta ? 0.f : bias[c];
#pragma unroll
    for (int mi = 0; mi < 4; ++mi) {
#pragma unroll
      for (int r = 0; r < 4; ++r) {
        const size_t idx = (size_t)(row0 + mi * 16 + r) * ldc + c;
        float v = acc[mi][ni][r] + bv;
        if (RELU_BF16_OUT) {
          v = v > 0.f ? v : 0.f;
          ((unsigned short*)C)[idx] = f2bf(v);
        } else {
          if (beta) v += ((float*)C)[idx];
          ((float*)C)[idx] = v;
        }
      }
    }
  }
}

// ---------------------------------------------------------------------------
extern "C" void kernel_launch(void* const* d_in, const int* in_sizes, int n_in,
                              void* d_out, int out_size, void* d_ws, size_t ws_size,
                              hipStream_t stream) {
  const float* X  = (const float*)d_in[0];  // [8192][1024]
  const float* W1 = (const float*)d_in[1];  // [1024][4096]
  const float* b1 = (const float*)d_in[2];  // [4096]
  const float* W2 = (const float*)d_in[3];  // [4096][1024]
  const float* b2 = (const float*)d_in[4];  // [1024]
  float* out = (float*)d_out;               // [8192][1024] f32

  const int M = 8192, H = 1024, I = 4096;
  const size_t MB = 1024 * 1024;

  char* ws = (char*)d_ws;
  unsigned short* W1t = (unsigned short*)ws;            // [I][H] bf16, 8 MB
  unsigned short* W2t = (unsigned short*)(ws + 8 * MB); // [H][I] bf16, 8 MB

  transpose_cvt<<<dim3(I / 32, H / 32), dim3(32, 8), 0, stream>>>(W1, W1t, H, I);
  transpose_cvt<<<dim3(H / 32, I / 32), dim3(32, 8), 0, stream>>>(W2, W2t, I, H);

  if (ws_size >= 80 * MB) {
    // Fast path. Xbf parked in d_out tail (fully consumed by L1 before the
    // single L2 dispatch writes d_out; stream-serialized).
    unsigned short* Xbf = (unsigned short*)((char*)d_out + 16 * MB);
    unsigned short* Hbf = (unsigned short*)(ws + 16 * MB);   // [M][I] bf16
    int n4 = (M * H) / 4;
    cvt_f32_bf16<<<(n4 + 255) / 256, 256, 0, stream>>>(X, Xbf, n4);
    // L1: Hbf = relu(X*W1+b1). 128x128 tiles, grid 32*64=2048 (8/CU avail).
    gemm_bf16<0, 128, 1><<<2048, 256, 0, stream>>>(
        Xbf, H, W1t, H, b1, Hbf, I, H, 0, I / 128);
    // L2: out = Hbf*W2+b2. 128x64 tiles, grid 16*64=1024 (4/CU avail).
    gemm_bf16<0, 64, 0><<<1024, 256, 0, stream>>>(
        Hbf, I, W2t, I, b2, out, H, I, 0, H / 64);
    return;
  }

  // Fallback: adaptive chunked path (round-2 logic, same kernels).
  int Ic, useXbf;
  unsigned short* Xbf = nullptr;
  unsigned short* Hc;
  if (ws_size >= 64 * MB) {
    Ic = 2048; useXbf = 1;
    Xbf = (unsigned short*)(ws + 16 * MB);
    Hc  = (unsigned short*)(ws + 32 * MB);
  } else if (ws_size >= 48 * MB) {
    Ic = 1024; useXbf = 1;
    Xbf = (unsigned short*)(ws + 16 * MB);
    Hc  = (unsigned short*)(ws + 32 * MB);
  } else if (ws_size >= 32 * MB) {
    Ic = 1024; useXbf = 0;
    Hc  = (unsigned short*)(ws + 16 * MB);
  } else if (ws_size >= 24 * MB) {
    Ic = 512;  useXbf = 0;
    Hc  = (unsigned short*)(ws + 16 * MB);
  } else if (ws_size >= 20 * MB) {
    Ic = 256;  useXbf = 0;
    Hc  = (unsigned short*)(ws + 16 * MB);
  } else {
    Ic = 128;  useXbf = 0;
    Hc  = (unsigned short*)(ws + 16 * MB);
  }

  if (useXbf) {
    int n4 = (M * H) / 4;
    cvt_f32_bf16<<<(n4 + 255) / 256, 256, 0, stream>>>(X, Xbf, n4);
  }

  const int nch = I / Ic;
  for (int c = 0; c < nch; ++c) {
    const int i0 = c * Ic;
    const int nbx1 = Ic / 128;
    if (useXbf)
      gemm_bf16<0, 128, 1><<<nbx1 * (M / 128), 256, 0, stream>>>(
          Xbf, H, W1t + (size_t)i0 * H, H, b1 + i0, Hc, Ic, H, 0, nbx1);
    else
      gemm_bf16<1, 128, 1><<<nbx1 * (M / 128), 256, 0, stream>>>(
          X, H, W1t + (size_t)i0 * H, H, b1 + i0, Hc, Ic, H, 0, nbx1);
    gemm_bf16<0, 64, 0><<<(H / 64) * (M / 128), 256, 0, stream>>>(
        Hc, Ic, W2t + i0, I, b2, out, H, Ic, c > 0, H / 64);
  }
}